// Round 8
// baseline (79.227 us; speedup 1.0000x reference)
//
#include <hip/hip_runtime.h>

// SpikingConv2D: y = conv3x3_same(tj, W) + (1 - D_i[0,f]); out = min(y, 1.0), NHWC fp32.
// R7: occupancy-first. Block = 224 px x 64 filters, 4 waves (2M x 2N), 48 KB LDS
// -> 3 blocks/CU resident, grid 896 (= 112 x 8 XCDs, bijective), ~12-14 waves/CU.
//  - A patch (6x58 halo rows, 32-ch quarter) LDS double-buffered; staged at quarter
//    start via global_load_lds; consumed only after the quarter-end __syncthreads
//    (full drain) -> cross-wave-safe by construction (R5 lesson).
//  - B straight from L2-resident Wt into registers, 2-tap prefetch (mod-3 pipeline,
//    all indices compile-time via template recursion -> stays in VGPRs).
//  - A granule XOR-swizzle swz(g)=g^((g>>3)&3) both-sides (R6: conflicts 2.6e5, free).
//  - Paired blocks (nb=0/1) adjacent on one XCD share the A region through L2.

#define BZ 32
#define CC 128
#define HH 56
#define WWD 56
#define HWP 3136
#define FF 128
#define PH 58
#define PW 58
#define AB_BYTES 24576      // per A buffer: 1536 granules * 16 B (1392 real)
#define A_GRAN_REAL 1392    // 6 rows * 58 px * 4 granules
#define NSTEP 36

typedef __attribute__((ext_vector_type(8))) __bf16 bf16x8;
typedef __attribute__((ext_vector_type(4))) float f32x4;
typedef __attribute__((ext_vector_type(8))) unsigned short us8;
typedef __attribute__((ext_vector_type(4))) float flt4;

__device__ __forceinline__ unsigned short f2bf(float f) {
  unsigned int u = __float_as_uint(f);
  unsigned int r = (u + 0x7FFFu + ((u >> 16) & 1u)) >> 16;
  return (unsigned short)r;
}

#define GLOAD_LDS16(g, l)                                                              \
  __builtin_amdgcn_global_load_lds((const __attribute__((address_space(1))) void*)(g), \
                                   (__attribute__((address_space(3))) void*)(l), 16, 0, 0)

__device__ __forceinline__ int swz(int g) { return g ^ ((g >> 3) & 3); }

// ---- W repack (linear): Wt slice S=q*9+r, granule g=f*4+kg holds channels
//      q*32+kg*8..+8 of filter f, tap r. 512 granules (8 KB) per slice. ----
__global__ void prep_w_kernel(const float* __restrict__ W, unsigned short* __restrict__ Wt) {
  int idx = blockIdx.x * 256 + threadIdx.x;
  if (idx >= NSTEP * 512) return;
  int qr = idx >> 9;
  int g = idx & 511;
  int q = qr / 9, r = qr - q * 9;
  int f = g >> 2, kg = g & 3;
  us8 v;
#pragma unroll
  for (int j = 0; j < 8; ++j) {
    int c = q * 32 + kg * 8 + j;
    v[j] = f2bf(W[(c * 9 + r) * FF + f]);
  }
  *reinterpret_cast<us8*>(Wt + (size_t)idx * 8) = v;
}

// ---- image prepass: x NCHW f32 -> xp padded NHWC bf16 [B][58][58][128] ----
__global__ __launch_bounds__(256) void prep_x_kernel(const float* __restrict__ x,
                                                     unsigned short* __restrict__ xp) {
  const int blk = blockIdx.x;
  const int b = blk / PH;
  const int ph = blk - b * PH;
  const int tid = threadIdx.x;
  unsigned short* dst = xp + (size_t)(b * PH + ph) * PW * CC;

  if (ph == 0 || ph == PH - 1) {
    us8 z;
#pragma unroll
    for (int k = 0; k < 8; ++k) z[k] = 0;
    for (int i = tid; i < PW * CC / 8; i += 256) reinterpret_cast<us8*>(dst)[i] = z;
    return;
  }

  __shared__ float sm[CC][57];
  const int h = ph - 1;
  {
    const int c = tid >> 1;
    const int half = tid & 1;
    const float* src = x + ((size_t)(b * CC + c)) * HWP + h * WWD + half * 28;
#pragma unroll
    for (int k = 0; k < 7; ++k) {
      flt4 v = *reinterpret_cast<const flt4*>(src + k * 4);
      sm[c][half * 28 + k * 4 + 0] = v[0];
      sm[c][half * 28 + k * 4 + 1] = v[1];
      sm[c][half * 28 + k * 4 + 2] = v[2];
      sm[c][half * 28 + k * 4 + 3] = v[3];
    }
  }
  __syncthreads();
  for (int i = tid; i < PW * 16; i += 256) {
    const int ww = i >> 4;
    const int cg = i & 15;
    us8 v;
    if (ww == 0 || ww == PW - 1) {
#pragma unroll
      for (int k = 0; k < 8; ++k) v[k] = 0;
    } else {
      const int w = ww - 1;
#pragma unroll
      for (int k = 0; k < 8; ++k) v[k] = f2bf(sm[cg * 8 + k][w]);
    }
    reinterpret_cast<us8*>(dst)[i] = v;
  }
}

// ---------------- main kernel ----------------
struct Ctx {
  const unsigned short* xp;
  const unsigned short* Wt;
  int tid;
  int srcA[6];         // xp element offsets per A staging chunk (quarter-0 base)
  int gbase[7];        // A-frag logical granule (dh=dw=0) per M-frag
  size_t gB2[2];       // B element offsets within a slice (j=0,1)
  f32x4 acc[7][2];
  bf16x8 bbuf[3][2];   // B 2-tap register pipeline (indices compile-time)
};

template <int S>
__device__ __forceinline__ void step(Ctx& c, unsigned char* lds) {
  constexpr int q = S / 9, r = S - q * 9;

  // A staging for quarter q+1, issued at tap 0 (drained by the r==8 barrier).
  if constexpr (r == 0 && q < 3) {
#pragma unroll
    for (int k = 0; k < 6; ++k)
      GLOAD_LDS16(c.xp + c.srcA[k] + (q + 1) * 32,
                  lds + ((q + 1) & 1) * AB_BYTES + (size_t)(k * 256 + c.tid) * 16);
  }
  // B register prefetch, 2 taps ahead.
  if constexpr (S + 2 < NSTEP) {
    const unsigned short* ws = c.Wt + (size_t)(S + 2) * 4096;
    c.bbuf[(S + 2) % 3][0] = *reinterpret_cast<const bf16x8*>(ws + c.gB2[0]);
    c.bbuf[(S + 2) % 3][1] = *reinterpret_cast<const bf16x8*>(ws + c.gB2[1]);
  }

  // compute tap r of quarter q
  constexpr int dh = r / 3 - 1, dw = r - (r / 3) * 3 - 1;
  constexpr int tapoff = (dh * PW + dw) * 4;
  const unsigned char* pa = lds + (q & 1) * AB_BYTES;
  bf16x8 af[7];
#pragma unroll
  for (int i = 0; i < 7; ++i) {
    int gt = c.gbase[i] + tapoff;
    af[i] = *reinterpret_cast<const bf16x8*>(pa + (swz(gt) << 4));
  }
#pragma unroll
  for (int i = 0; i < 7; ++i)
#pragma unroll
    for (int j = 0; j < 2; ++j)
      c.acc[i][j] =
          __builtin_amdgcn_mfma_f32_16x16x32_bf16(af[i], c.bbuf[S % 3][j], c.acc[i][j], 0, 0, 0);

  // quarter-end: full drain + barrier makes next quarter's A visible to all waves.
  if constexpr (r == 8 && q < 3) __syncthreads();
}

template <int S>
__device__ __forceinline__ void do_steps(Ctx& c, unsigned char* lds) {
  step<S>(c, lds);
  if constexpr (S + 1 < NSTEP) do_steps<S + 1>(c, lds);
}

__global__ __launch_bounds__(256, 3) void spiking_conv_main(
    const unsigned short* __restrict__ xp, const unsigned short* __restrict__ Wt,
    const float* __restrict__ Di, float* __restrict__ out) {
  __shared__ unsigned char lds[2 * AB_BYTES];  // 48 KB

  const int bid = blockIdx.x;
  const int wg2 = (bid & 7) * 112 + (bid >> 3);  // 896 = 112 per XCD, bijective
  const int nb = wg2 & 1;                        // filter half (paired blocks share A)
  const int wg = wg2 >> 1;
  const int b = wg / 14;
  const int rg = wg - b * 14;
  const int h0 = rg * 4;

  Ctx c;
  c.xp = xp;
  c.Wt = Wt;
  const int tid = threadIdx.x;
  c.tid = tid;
  const int lane = tid & 63, wv = tid >> 6;
  const int wr = wv >> 1, wc = wv & 1;
  const int frow = lane & 15, kg = lane >> 4;

#pragma unroll
  for (int k = 0; k < 6; ++k) {
    int gp = k * 256 + tid;
    int g = (gp >= A_GRAN_REAL) ? 0 : swz(gp);  // pad: harmless in-bounds source
    int prow = g / 232;                          // patch row (58 px * 4 granules)
    int rem = g - prow * 232;
    int px = rem >> 2;
    int kg2 = rem & 3;
    c.srcA[k] = ((b * PH + h0 + prow) * PW + px) * CC + kg2 * 8;
  }
#pragma unroll
  for (int i = 0; i < 7; ++i) {
    int t = 16 * i + frow;  // 0..111 within wave's 112-px half
    int rowb = (t >= 56) ? 1 : 0;
    int col = t - 56 * rowb;
    c.gbase[i] = ((2 * wr + rowb + 1) * PW + (col + 1)) * 4 + kg;
  }
#pragma unroll
  for (int j = 0; j < 2; ++j)
    c.gB2[j] = (size_t)(((nb * 64 + wc * 32 + 16 * j + frow) * 4 + kg)) * 8;

  const f32x4 zero = {0.0f, 0.0f, 0.0f, 0.0f};
#pragma unroll
  for (int i = 0; i < 7; ++i)
#pragma unroll
    for (int j = 0; j < 2; ++j) c.acc[i][j] = zero;

  // prologue: A quarter 0 -> buf 0; B slices 0,1 -> bbuf[0],bbuf[1].
#pragma unroll
  for (int k = 0; k < 6; ++k)
    GLOAD_LDS16(xp + c.srcA[k], lds + (size_t)(k * 256 + tid) * 16);
#pragma unroll
  for (int j = 0; j < 2; ++j) {
    c.bbuf[0][j] = *reinterpret_cast<const bf16x8*>(Wt + c.gB2[j]);
    c.bbuf[1][j] = *reinterpret_cast<const bf16x8*>(Wt + 4096 + c.gB2[j]);
  }
  __syncthreads();  // drains A staging (vmcnt(0)) before any wave reads buf 0

  do_steps<0>(c, lds);

  // epilogue: + (1 - D_i[f]), clamp 1.0, NHWC fp32
#pragma unroll
  for (int j = 0; j < 2; ++j) {
    const int col = nb * 64 + wc * 32 + 16 * j + frow;
    const float thr = 1.0f - Di[col];
#pragma unroll
    for (int i = 0; i < 7; ++i) {
      const int bt = 16 * i + kg * 4;  // 4-run never crosses the 56 boundary
      const int rowb = (bt >= 56) ? 1 : 0;
      const int wl0 = bt - 56 * rowb;
      const int orow = h0 + 2 * wr + rowb;
      const size_t obase = ((size_t)b * HWP + (size_t)orow * WWD + wl0) * FF + col;
#pragma unroll
      for (int qq = 0; qq < 4; ++qq) {
        float v = c.acc[i][j][qq] + thr;
        out[obase + (size_t)qq * FF] = fminf(v, 1.0f);
      }
    }
  }
}

// ---- fallback (round-0 style, reads W directly) ----
__global__ __launch_bounds__(256) void spiking_conv_fallback(
    const float* __restrict__ x, const float* __restrict__ Wf,
    const float* __restrict__ Di, float* __restrict__ out) {
  __shared__ unsigned short Asm2[128][32];
  __shared__ unsigned short Bsm2[128][32];
  const int tid = threadIdx.x;
  const int m0 = blockIdx.x * 128;
  const int mi = tid & 127;
  const int half = tid >> 7;
  const int m = m0 + mi;
  const int bimg = m / HWP;
  const int p = m - bimg * HWP;
  const int h = p / WWD;
  const int w = p - h * WWD;
  const int baseA = (bimg * CC) * HWP + h * WWD + w;
  const int lane = tid & 63;
  const int wid = tid >> 6;
  const int wr = wid >> 1;
  const int wc = wid & 1;
  const int frow = lane & 15;
  const int kg = lane >> 4;
  f32x4 acc[4][4];
  const f32x4 zero = {0.0f, 0.0f, 0.0f, 0.0f};
#pragma unroll
  for (int i = 0; i < 4; ++i)
#pragma unroll
    for (int j = 0; j < 4; ++j) acc[i][j] = zero;
  for (int r = 0; r < 9; ++r) {
    const int dh = r / 3 - 1;
    const int dw = r - (r / 3) * 3 - 1;
    const int hh = h + dh;
    const int ww2 = w + dw;
    const bool valid = ((unsigned)hh < (unsigned)HH) && ((unsigned)ww2 < (unsigned)WWD);
    const int aoff2 = baseA + dh * WWD + dw + half * 16 * HWP;
    for (int c0 = 0; c0 < CC; c0 += 32) {
      __syncthreads();
      {
        const float* src = x + aoff2 + c0 * HWP;
        us8 v0, v1;
#pragma unroll
        for (int i = 0; i < 8; ++i) {
          float f0 = valid ? src[i * HWP] : 0.0f;
          float f1 = valid ? src[(i + 8) * HWP] : 0.0f;
          v0[i] = f2bf(f0);
          v1[i] = f2bf(f1);
        }
        *reinterpret_cast<us8*>(&Asm2[mi][half * 16]) = v0;
        *reinterpret_cast<us8*>(&Asm2[mi][half * 16 + 8]) = v1;
      }
      {
        us8 v0, v1;
#pragma unroll
        for (int i = 0; i < 8; ++i) {
          int cc2 = c0 + half * 16 + i;
          v0[i] = f2bf(Wf[(cc2 * 9 + r) * FF + mi]);
          v1[i] = f2bf(Wf[((cc2 + 8) * 9 + r) * FF + mi]);
        }
        *reinterpret_cast<us8*>(&Bsm2[mi][half * 16]) = v0;
        *reinterpret_cast<us8*>(&Bsm2[mi][half * 16 + 8]) = v1;
      }
      __syncthreads();
      bf16x8 af[4], bfr[4];
#pragma unroll
      for (int i = 0; i < 4; ++i)
        af[i] = *reinterpret_cast<const bf16x8*>(&Asm2[wr * 64 + i * 16 + frow][kg * 8]);
#pragma unroll
      for (int j = 0; j < 4; ++j)
        bfr[j] = *reinterpret_cast<const bf16x8*>(&Bsm2[wc * 64 + j * 16 + frow][kg * 8]);
#pragma unroll
      for (int i = 0; i < 4; ++i)
#pragma unroll
        for (int j = 0; j < 4; ++j)
          acc[i][j] = __builtin_amdgcn_mfma_f32_16x16x32_bf16(af[i], bfr[j], acc[i][j], 0, 0, 0);
    }
  }
#pragma unroll
  for (int j = 0; j < 4; ++j) {
    const int col = wc * 64 + j * 16 + frow;
    const float thr = 1.0f - Di[col];
#pragma unroll
    for (int i = 0; i < 4; ++i) {
      const int rbase = m0 + wr * 64 + i * 16 + kg * 4;
#pragma unroll
      for (int qq = 0; qq < 4; ++qq) {
        float v = acc[i][j][qq] + thr;
        out[(size_t)(rbase + qq) * FF + col] = fminf(v, 1.0f);
      }
    }
  }
}

extern "C" void kernel_launch(void* const* d_in, const int* in_sizes, int n_in,
                              void* d_out, int out_size, void* d_ws, size_t ws_size,
                              hipStream_t stream) {
  const float* tj = (const float*)d_in[0];
  const float* W = (const float*)d_in[1];
  const float* Di = (const float*)d_in[2];
  float* out = (float*)d_out;

  const size_t wt_bytes = (size_t)NSTEP * 512 * 16;        // 294912
  const size_t xp_bytes = (size_t)BZ * PH * PW * CC * 2;   // 27557888
  unsigned short* Wt = (unsigned short*)d_ws;
  unsigned short* xp = (unsigned short*)((char*)d_ws + wt_bytes);

  bool fast = (ws_size >= wt_bytes + xp_bytes);
  if (fast) {
    prep_w_kernel<<<72, 256, 0, stream>>>(W, Wt);
    prep_x_kernel<<<BZ * PH, 256, 0, stream>>>(tj, xp);
    spiking_conv_main<<<896, 256, 0, stream>>>(xp, Wt, Di, out);
    if (hipGetLastError() != hipSuccess) fast = false;
  }
  if (!fast) {
    spiking_conv_fallback<<<100352 / 128, 256, 0, stream>>>(tj, W, Di, out);
  }
}

// Round 9
// 70.786 us; speedup vs baseline: 1.1193x; 1.1193x over previous
//
#include <hip/hip_runtime.h>

// SpikingConv2D: y = conv3x3_same(tj, W) + (1 - D_i[0,f]); out = min(y, 1.0), NHWC fp32.
// R8: R6 structure + register-liberated explicit pipeline.
//  - Block = 4 rows x 56 = 224 px x 128 f, 4 waves (7M x 4N frags), grid 448
//    (XCD-bijective), 48 KB LDS A double-buffer, barriers ONLY at quarter ends (4).
//  - KEY CHANGE vs R6: __launch_bounds__(256,1) (R6/R7 launch_bounds starved regs ->
//    compiler serialized ds_read vs MFMA; VGPR_Count is this round's readout) and an
//    EXPLICIT af double-buffer: step S prefetches tap S+1's 7 A-frags (static parity),
//    MFMAs consume tap S's frags loaded last step -> LDS latency hidden by dataflow.
//  - B from L2-resident Wt, 2-deep static register pipeline (bcur/bnext by parity).
//  - A-staging global_load_lds issued at tap r==6 AFTER that tap's B load: no B-use
//    vmcnt wait ever queues behind a staging load (FIFO suffix analysis); quarter-end
//    __syncthreads (vmcnt0+lgkmcnt0 drain) makes staging visible -> race-free.
//  - A granule XOR-swizzle swz(g)=g^((g>>3)&3) both-sides (conflicts ~2.6e5, free).

#define BZ 32
#define CC 128
#define HH 56
#define WWD 56
#define HWP 3136
#define FF 128
#define PH 58
#define PW 58
#define AB_BYTES 24576      // per A buffer: 1536 granules * 16 B (1392 real)
#define A_GRAN_REAL 1392    // 6 rows * 58 px * 4 granules
#define NSTEP 36

typedef __attribute__((ext_vector_type(8))) __bf16 bf16x8;
typedef __attribute__((ext_vector_type(4))) float f32x4;
typedef __attribute__((ext_vector_type(8))) unsigned short us8;
typedef __attribute__((ext_vector_type(4))) float flt4;

__device__ __forceinline__ unsigned short f2bf(float f) {
  unsigned int u = __float_as_uint(f);
  unsigned int r = (u + 0x7FFFu + ((u >> 16) & 1u)) >> 16;
  return (unsigned short)r;
}

#define GLOAD_LDS16(g, l)                                                              \
  __builtin_amdgcn_global_load_lds((const __attribute__((address_space(1))) void*)(g), \
                                   (__attribute__((address_space(3))) void*)(l), 16, 0, 0)

__device__ __forceinline__ int swz(int g) { return g ^ ((g >> 3) & 3); }

// ---- W repack (linear): Wt slice S=q*9+r, granule g=f*4+kg holds channels
//      q*32+kg*8..+8 of filter f, tap r. 512 granules (8 KB) per slice. ----
__global__ void prep_w_kernel(const float* __restrict__ W, unsigned short* __restrict__ Wt) {
  int idx = blockIdx.x * 256 + threadIdx.x;
  if (idx >= NSTEP * 512) return;
  int qr = idx >> 9;
  int g = idx & 511;
  int q = qr / 9, r = qr - q * 9;
  int f = g >> 2, kg = g & 3;
  us8 v;
#pragma unroll
  for (int j = 0; j < 8; ++j) {
    int c = q * 32 + kg * 8 + j;
    v[j] = f2bf(W[(c * 9 + r) * FF + f]);
  }
  *reinterpret_cast<us8*>(Wt + (size_t)idx * 8) = v;
}

// ---- image prepass: x NCHW f32 -> xp padded NHWC bf16 [B][58][58][128] ----
__global__ __launch_bounds__(256) void prep_x_kernel(const float* __restrict__ x,
                                                     unsigned short* __restrict__ xp) {
  const int blk = blockIdx.x;
  const int b = blk / PH;
  const int ph = blk - b * PH;
  const int tid = threadIdx.x;
  unsigned short* dst = xp + (size_t)(b * PH + ph) * PW * CC;

  if (ph == 0 || ph == PH - 1) {
    us8 z;
#pragma unroll
    for (int k = 0; k < 8; ++k) z[k] = 0;
    for (int i = tid; i < PW * CC / 8; i += 256) reinterpret_cast<us8*>(dst)[i] = z;
    return;
  }

  __shared__ float sm[CC][57];
  const int h = ph - 1;
  {
    const int c = tid >> 1;
    const int half = tid & 1;
    const float* src = x + ((size_t)(b * CC + c)) * HWP + h * WWD + half * 28;
#pragma unroll
    for (int k = 0; k < 7; ++k) {
      flt4 v = *reinterpret_cast<const flt4*>(src + k * 4);
      sm[c][half * 28 + k * 4 + 0] = v[0];
      sm[c][half * 28 + k * 4 + 1] = v[1];
      sm[c][half * 28 + k * 4 + 2] = v[2];
      sm[c][half * 28 + k * 4 + 3] = v[3];
    }
  }
  __syncthreads();
  for (int i = tid; i < PW * 16; i += 256) {
    const int ww = i >> 4;
    const int cg = i & 15;
    us8 v;
    if (ww == 0 || ww == PW - 1) {
#pragma unroll
      for (int k = 0; k < 8; ++k) v[k] = 0;
    } else {
      const int w = ww - 1;
#pragma unroll
      for (int k = 0; k < 8; ++k) v[k] = f2bf(sm[cg * 8 + k][w]);
    }
    reinterpret_cast<us8*>(dst)[i] = v;
  }
}

// ---------------- main kernel ----------------
struct Ctx {
  const unsigned short* xp;
  const unsigned short* Wt;
  int tid;
  int srcA[6];          // xp element offsets per A staging chunk (quarter-0 base)
  int gbase[7];         // A-frag logical granule (dh=dw=0) per M-frag
  int gB[4];            // B element offsets within a slice (j=0..3)
  f32x4 acc[7][4];
  bf16x8 af[2][7];      // A-frag double buffer (parity = tap index & 1)
  bf16x8 bb[2][4];      // B-frag double buffer (parity = slice index & 1)
};

template <int R>
__device__ __forceinline__ void load_af(Ctx& c, const unsigned char* pa, bf16x8 (&dst)[7]) {
  constexpr int dh = R / 3 - 1, dw = R - (R / 3) * 3 - 1;
  constexpr int tapoff = (dh * PW + dw) * 4;  // logical granules
#pragma unroll
  for (int i = 0; i < 7; ++i) {
    int gt = c.gbase[i] + tapoff;
    dst[i] = *reinterpret_cast<const bf16x8*>(pa + (swz(gt) << 4));
  }
}

template <int S>
__device__ __forceinline__ void step(Ctx& c, unsigned char* lds) {
  constexpr int q = S / 9, r = S - q * 9;
  const unsigned char* pa = lds + (q & 1) * AB_BYTES;

  // cold-start A-frags at quarter begin (af prefetch can't cross the barrier)
  if constexpr (r == 0) load_af<0>(c, pa, c.af[S & 1]);

  // B prefetch for tap S+1 (global, L2-resident; ~1 tap of latency cover)
  if constexpr (S + 1 < NSTEP) {
    const unsigned short* ws = c.Wt + (size_t)(S + 1) * 4096;
#pragma unroll
    for (int j = 0; j < 4; ++j)
      c.bb[(S + 1) & 1][j] = *reinterpret_cast<const bf16x8*>(ws + c.gB[j]);
  }
  // A-staging for quarter q+1: issued AFTER this tap's B load, so no later B-use
  // vmcnt wait queues behind these; drained by the quarter-end __syncthreads.
  if constexpr (r == 6 && q < 3) {
#pragma unroll
    for (int k = 0; k < 6; ++k)
      GLOAD_LDS16(c.xp + c.srcA[k] + (q + 1) * 32,
                  lds + ((q + 1) & 1) * AB_BYTES + (size_t)(k * 256 + c.tid) * 16);
  }
  // A-frag prefetch for next tap (same quarter only)
  if constexpr (r < 8) load_af<r + 1>(c, pa, c.af[(S + 1) & 1]);

  // MFMA cluster on current tap's frags (loaded last step / cold above)
#pragma unroll
  for (int i = 0; i < 7; ++i)
#pragma unroll
    for (int j = 0; j < 4; ++j)
      c.acc[i][j] =
          __builtin_amdgcn_mfma_f32_16x16x32_bf16(c.af[S & 1][i], c.bb[S & 1][j], c.acc[i][j], 0, 0, 0);

  // quarter-end: full drain + barrier makes next quarter's A visible to all waves.
  if constexpr (r == 8 && q < 3) __syncthreads();
}

template <int S>
__device__ __forceinline__ void do_steps(Ctx& c, unsigned char* lds) {
  step<S>(c, lds);
  if constexpr (S + 1 < NSTEP) do_steps<S + 1>(c, lds);
}

__global__ __launch_bounds__(256, 1) void spiking_conv_main(
    const unsigned short* __restrict__ xp, const unsigned short* __restrict__ Wt,
    const float* __restrict__ Di, float* __restrict__ out) {
  __shared__ unsigned char lds[2 * AB_BYTES];  // 48 KB

  const int bid = blockIdx.x;
  const int wg = (bid & 7) * 56 + (bid >> 3);  // 448 = 56 per XCD, bijective
  const int b = wg / 14;
  const int rg = wg - b * 14;
  const int h0 = rg * 4;

  Ctx c;
  c.xp = xp;
  c.Wt = Wt;
  const int tid = threadIdx.x;
  c.tid = tid;
  const int lane = tid & 63, wv = tid >> 6;
  const int wr = wv >> 1, wc = wv & 1;
  const int frow = lane & 15, kg = lane >> 4;

#pragma unroll
  for (int k = 0; k < 6; ++k) {
    int gp = k * 256 + tid;
    int g = (gp >= A_GRAN_REAL) ? 0 : swz(gp);  // pad: harmless in-bounds source
    int prow = g / 232;                          // patch row (58 px * 4 granules)
    int rem = g - prow * 232;
    int px = rem >> 2;
    int kg2 = rem & 3;
    c.srcA[k] = ((b * PH + h0 + prow) * PW + px) * CC + kg2 * 8;
  }
#pragma unroll
  for (int i = 0; i < 7; ++i) {
    int t = 16 * i + frow;  // 0..111 within wave's 112-px half
    int rowb = (t >= 56) ? 1 : 0;
    int col = t - 56 * rowb;
    c.gbase[i] = ((2 * wr + rowb + 1) * PW + (col + 1)) * 4 + kg;
  }
#pragma unroll
  for (int j = 0; j < 4; ++j)
    c.gB[j] = ((wc * 64 + 16 * j + frow) * 4 + kg) * 8;

  const f32x4 zero = {0.0f, 0.0f, 0.0f, 0.0f};
#pragma unroll
  for (int i = 0; i < 7; ++i)
#pragma unroll
    for (int j = 0; j < 4; ++j) c.acc[i][j] = zero;

  // prologue: A quarter 0 -> buf 0 (LDS), B slice 0 -> bb[0].
#pragma unroll
  for (int k = 0; k < 6; ++k)
    GLOAD_LDS16(xp + c.srcA[k], lds + (size_t)(k * 256 + tid) * 16);
#pragma unroll
  for (int j = 0; j < 4; ++j)
    c.bb[0][j] = *reinterpret_cast<const bf16x8*>(Wt + c.gB[j]);
  __syncthreads();  // drains A staging (vmcnt(0)) before any wave reads buf 0

  do_steps<0>(c, lds);

  // epilogue: + (1 - D_i[f]), clamp 1.0, NHWC fp32
#pragma unroll
  for (int j = 0; j < 4; ++j) {
    const int col = wc * 64 + 16 * j + frow;
    const float thr = 1.0f - Di[col];
#pragma unroll
    for (int i = 0; i < 7; ++i) {
      const int bt = 16 * i + kg * 4;  // 4-run never crosses the 56 boundary
      const int rowb = (bt >= 56) ? 1 : 0;
      const int wl0 = bt - 56 * rowb;
      const int orow = h0 + 2 * wr + rowb;
      const size_t obase = ((size_t)b * HWP + (size_t)orow * WWD + wl0) * FF + col;
#pragma unroll
      for (int qq = 0; qq < 4; ++qq) {
        float v = c.acc[i][j][qq] + thr;
        out[obase + (size_t)qq * FF] = fminf(v, 1.0f);
      }
    }
  }
}

// ---- fallback (round-0 style, reads W directly) ----
__global__ __launch_bounds__(256) void spiking_conv_fallback(
    const float* __restrict__ x, const float* __restrict__ Wf,
    const float* __restrict__ Di, float* __restrict__ out) {
  __shared__ unsigned short Asm2[128][32];
  __shared__ unsigned short Bsm2[128][32];
  const int tid = threadIdx.x;
  const int m0 = blockIdx.x * 128;
  const int mi = tid & 127;
  const int half = tid >> 7;
  const int m = m0 + mi;
  const int bimg = m / HWP;
  const int p = m - bimg * HWP;
  const int h = p / WWD;
  const int w = p - h * WWD;
  const int baseA = (bimg * CC) * HWP + h * WWD + w;
  const int lane = tid & 63;
  const int wid = tid >> 6;
  const int wr = wid >> 1;
  const int wc = wid & 1;
  const int frow = lane & 15;
  const int kg = lane >> 4;
  f32x4 acc[4][4];
  const f32x4 zero = {0.0f, 0.0f, 0.0f, 0.0f};
#pragma unroll
  for (int i = 0; i < 4; ++i)
#pragma unroll
    for (int j = 0; j < 4; ++j) acc[i][j] = zero;
  for (int r = 0; r < 9; ++r) {
    const int dh = r / 3 - 1;
    const int dw = r - (r / 3) * 3 - 1;
    const int hh = h + dh;
    const int ww2 = w + dw;
    const bool valid = ((unsigned)hh < (unsigned)HH) && ((unsigned)ww2 < (unsigned)WWD);
    const int aoff2 = baseA + dh * WWD + dw + half * 16 * HWP;
    for (int c0 = 0; c0 < CC; c0 += 32) {
      __syncthreads();
      {
        const float* src = x + aoff2 + c0 * HWP;
        us8 v0, v1;
#pragma unroll
        for (int i = 0; i < 8; ++i) {
          float f0 = valid ? src[i * HWP] : 0.0f;
          float f1 = valid ? src[(i + 8) * HWP] : 0.0f;
          v0[i] = f2bf(f0);
          v1[i] = f2bf(f1);
        }
        *reinterpret_cast<us8*>(&Asm2[mi][half * 16]) = v0;
        *reinterpret_cast<us8*>(&Asm2[mi][half * 16 + 8]) = v1;
      }
      {
        us8 v0, v1;
#pragma unroll
        for (int i = 0; i < 8; ++i) {
          int cc2 = c0 + half * 16 + i;
          v0[i] = f2bf(Wf[(cc2 * 9 + r) * FF + mi]);
          v1[i] = f2bf(Wf[((cc2 + 8) * 9 + r) * FF + mi]);
        }
        *reinterpret_cast<us8*>(&Bsm2[mi][half * 16]) = v0;
        *reinterpret_cast<us8*>(&Bsm2[mi][half * 16 + 8]) = v1;
      }
      __syncthreads();
      bf16x8 af[4], bfr[4];
#pragma unroll
      for (int i = 0; i < 4; ++i)
        af[i] = *reinterpret_cast<const bf16x8*>(&Asm2[wr * 64 + i * 16 + frow][kg * 8]);
#pragma unroll
      for (int j = 0; j < 4; ++j)
        bfr[j] = *reinterpret_cast<const bf16x8*>(&Bsm2[wc * 64 + j * 16 + frow][kg * 8]);
#pragma unroll
      for (int i = 0; i < 4; ++i)
#pragma unroll
        for (int j = 0; j < 4; ++j)
          acc[i][j] = __builtin_amdgcn_mfma_f32_16x16x32_bf16(af[i], bfr[j], acc[i][j], 0, 0, 0);
    }
  }
#pragma unroll
  for (int j = 0; j < 4; ++j) {
    const int col = wc * 64 + j * 16 + frow;
    const float thr = 1.0f - Di[col];
#pragma unroll
    for (int i = 0; i < 4; ++i) {
      const int rbase = m0 + wr * 64 + i * 16 + kg * 4;
#pragma unroll
      for (int qq = 0; qq < 4; ++qq) {
        float v = acc[i][j][qq] + thr;
        out[(size_t)(rbase + qq) * FF + col] = fminf(v, 1.0f);
      }
    }
  }
}

extern "C" void kernel_launch(void* const* d_in, const int* in_sizes, int n_in,
                              void* d_out, int out_size, void* d_ws, size_t ws_size,
                              hipStream_t stream) {
  const float* tj = (const float*)d_in[0];
  const float* W = (const float*)d_in[1];
  const float* Di = (const float*)d_in[2];
  float* out = (float*)d_out;

  const size_t wt_bytes = (size_t)NSTEP * 512 * 16;        // 294912
  const size_t xp_bytes = (size_t)BZ * PH * PW * CC * 2;   // 27557888
  unsigned short* Wt = (unsigned short*)d_ws;
  unsigned short* xp = (unsigned short*)((char*)d_ws + wt_bytes);

  bool fast = (ws_size >= wt_bytes + xp_bytes);
  if (fast) {
    prep_w_kernel<<<72, 256, 0, stream>>>(W, Wt);
    prep_x_kernel<<<BZ * PH, 256, 0, stream>>>(tj, xp);
    spiking_conv_main<<<448, 256, 0, stream>>>(xp, Wt, Di, out);
    if (hipGetLastError() != hipSuccess) fast = false;
  }
  if (!fast) {
    spiking_conv_fallback<<<100352 / 128, 256, 0, stream>>>(tj, W, Di, out);
  }
}

// Round 10
// 61.593 us; speedup vs baseline: 1.2863x; 1.1492x over previous
//
#include <hip/hip_runtime.h>

// SpikingConv2D: y = conv3x3_same(tj, W) + (1 - D_i[0,f]); out = min(y, 1.0), NHWC fp32.
// R9: R8 structure, register-trimmed for 2 blocks/CU (the R6/R8 synthesis).
//  - Per-SIMD MFMA arithmetic (R8 lesson): one 16x16x32 MFMA ~19.4 cyc/SIMD; a tap's
//    28-MFMA cluster = 543 cyc. Floor = 14.3 us. Fill strategy: TWO waves/SIMD
//    co-scheduling (m114), each wave's lgkm/vmem stalls covered by the other's MFMAs.
//  - af SINGLE buffer (-28 VGPR vs R8): load 7 frags, wait, 28 MFMAs. 79% solo duty
//    cycle -> 2 waves saturate the pipe without intra-wave load/MFMA overlap.
//  - __launch_bounds__(256,2): cap 256 regs >= ~204 demand -> no spill (R7 lesson),
//    2 waves/SIMD residency (R8 blocker).
//  - Unchanged proven pieces: 448 blocks XCD-bijective (one fill at 2 blocks/CU),
//    48 KB LDS A quarter double-buffer, barriers ONLY at quarter ends (4 total),
//    B from L2-resident Wt w/ parity double-buffer (543-cyc cover vs ~300-cyc L2),
//    A-staging at r==6 issued AFTER B loads (vmcnt FIFO-safe, 3-tap HBM cover),
//    granule XOR-swizzle swz(g)=g^((g>>3)&3) both-sides.

#define BZ 32
#define CC 128
#define HH 56
#define WWD 56
#define HWP 3136
#define FF 128
#define PH 58
#define PW 58
#define AB_BYTES 24576      // per A buffer: 1536 granules * 16 B (1392 real)
#define A_GRAN_REAL 1392    // 6 rows * 58 px * 4 granules
#define NSTEP 36

typedef __attribute__((ext_vector_type(8))) __bf16 bf16x8;
typedef __attribute__((ext_vector_type(4))) float f32x4;
typedef __attribute__((ext_vector_type(8))) unsigned short us8;
typedef __attribute__((ext_vector_type(4))) float flt4;

__device__ __forceinline__ unsigned short f2bf(float f) {
  unsigned int u = __float_as_uint(f);
  unsigned int r = (u + 0x7FFFu + ((u >> 16) & 1u)) >> 16;
  return (unsigned short)r;
}

#define GLOAD_LDS16(g, l)                                                              \
  __builtin_amdgcn_global_load_lds((const __attribute__((address_space(1))) void*)(g), \
                                   (__attribute__((address_space(3))) void*)(l), 16, 0, 0)

__device__ __forceinline__ int swz(int g) { return g ^ ((g >> 3) & 3); }

// ---- W repack (linear): Wt slice S=q*9+r, granule g=f*4+kg holds channels
//      q*32+kg*8..+8 of filter f, tap r. 512 granules (8 KB) per slice. ----
__global__ void prep_w_kernel(const float* __restrict__ W, unsigned short* __restrict__ Wt) {
  int idx = blockIdx.x * 256 + threadIdx.x;
  if (idx >= NSTEP * 512) return;
  int qr = idx >> 9;
  int g = idx & 511;
  int q = qr / 9, r = qr - q * 9;
  int f = g >> 2, kg = g & 3;
  us8 v;
#pragma unroll
  for (int j = 0; j < 8; ++j) {
    int c = q * 32 + kg * 8 + j;
    v[j] = f2bf(W[(c * 9 + r) * FF + f]);
  }
  *reinterpret_cast<us8*>(Wt + (size_t)idx * 8) = v;
}

// ---- image prepass: x NCHW f32 -> xp padded NHWC bf16 [B][58][58][128] ----
__global__ __launch_bounds__(256) void prep_x_kernel(const float* __restrict__ x,
                                                     unsigned short* __restrict__ xp) {
  const int blk = blockIdx.x;
  const int b = blk / PH;
  const int ph = blk - b * PH;
  const int tid = threadIdx.x;
  unsigned short* dst = xp + (size_t)(b * PH + ph) * PW * CC;

  if (ph == 0 || ph == PH - 1) {
    us8 z;
#pragma unroll
    for (int k = 0; k < 8; ++k) z[k] = 0;
    for (int i = tid; i < PW * CC / 8; i += 256) reinterpret_cast<us8*>(dst)[i] = z;
    return;
  }

  __shared__ float sm[CC][57];
  const int h = ph - 1;
  {
    const int c = tid >> 1;
    const int half = tid & 1;
    const float* src = x + ((size_t)(b * CC + c)) * HWP + h * WWD + half * 28;
#pragma unroll
    for (int k = 0; k < 7; ++k) {
      flt4 v = *reinterpret_cast<const flt4*>(src + k * 4);
      sm[c][half * 28 + k * 4 + 0] = v[0];
      sm[c][half * 28 + k * 4 + 1] = v[1];
      sm[c][half * 28 + k * 4 + 2] = v[2];
      sm[c][half * 28 + k * 4 + 3] = v[3];
    }
  }
  __syncthreads();
  for (int i = tid; i < PW * 16; i += 256) {
    const int ww = i >> 4;
    const int cg = i & 15;
    us8 v;
    if (ww == 0 || ww == PW - 1) {
#pragma unroll
      for (int k = 0; k < 8; ++k) v[k] = 0;
    } else {
      const int w = ww - 1;
#pragma unroll
      for (int k = 0; k < 8; ++k) v[k] = f2bf(sm[cg * 8 + k][w]);
    }
    reinterpret_cast<us8*>(dst)[i] = v;
  }
}

// ---------------- main kernel ----------------
struct Ctx {
  const unsigned short* xp;
  const unsigned short* Wt;
  int tid;
  int srcA[6];          // xp element offsets per A staging chunk (quarter-0 base)
  int gbase[7];         // A-frag logical granule (dh=dw=0) per M-frag
  int gB[4];            // B element offsets within a slice (j=0..3)
  f32x4 acc[7][4];
  bf16x8 bb[2][4];      // B-frag double buffer (parity = slice index & 1)
};

template <int S>
__device__ __forceinline__ void step(Ctx& c, unsigned char* lds) {
  constexpr int q = S / 9, r = S - q * 9;
  const unsigned char* pa = lds + (q & 1) * AB_BYTES;

  // B prefetch for tap S+1 (global, L2-resident; ~543 cyc of MFMA cover)
  if constexpr (S + 1 < NSTEP) {
    const unsigned short* ws = c.Wt + (size_t)(S + 1) * 4096;
#pragma unroll
    for (int j = 0; j < 4; ++j)
      c.bb[(S + 1) & 1][j] = *reinterpret_cast<const bf16x8*>(ws + c.gB[j]);
  }
  // A-staging for quarter q+1: AFTER this tap's B loads (B-use vmcnt waits never
  // queue behind these); drained by the quarter-end __syncthreads (3 taps later).
  if constexpr (r == 6 && q < 3) {
#pragma unroll
    for (int k = 0; k < 6; ++k)
      GLOAD_LDS16(c.xp + c.srcA[k] + (q + 1) * 32,
                  lds + ((q + 1) & 1) * AB_BYTES + (size_t)(k * 256 + c.tid) * 16);
  }

  // A-frags for THIS tap (single buffer; the other wave on the SIMD covers the wait)
  constexpr int dh = r / 3 - 1, dw = r - (r / 3) * 3 - 1;
  constexpr int tapoff = (dh * PW + dw) * 4;  // logical granules
  bf16x8 af[7];
#pragma unroll
  for (int i = 0; i < 7; ++i) {
    int gt = c.gbase[i] + tapoff;
    af[i] = *reinterpret_cast<const bf16x8*>(pa + (swz(gt) << 4));
  }

  // 28-MFMA cluster (543 cyc of SIMD matrix-pipe time)
#pragma unroll
  for (int i = 0; i < 7; ++i)
#pragma unroll
    for (int j = 0; j < 4; ++j)
      c.acc[i][j] =
          __builtin_amdgcn_mfma_f32_16x16x32_bf16(af[i], c.bb[S & 1][j], c.acc[i][j], 0, 0, 0);

  // quarter-end: full drain + barrier makes next quarter's A visible to all waves.
  if constexpr (r == 8 && q < 3) __syncthreads();
}

template <int S>
__device__ __forceinline__ void do_steps(Ctx& c, unsigned char* lds) {
  step<S>(c, lds);
  if constexpr (S + 1 < NSTEP) do_steps<S + 1>(c, lds);
}

__global__ __launch_bounds__(256, 2) void spiking_conv_main(
    const unsigned short* __restrict__ xp, const unsigned short* __restrict__ Wt,
    const float* __restrict__ Di, float* __restrict__ out) {
  __shared__ unsigned char lds[2 * AB_BYTES];  // 48 KB

  const int bid = blockIdx.x;
  const int wg = (bid & 7) * 56 + (bid >> 3);  // 448 = 56 per XCD, bijective
  const int b = wg / 14;
  const int rg = wg - b * 14;
  const int h0 = rg * 4;

  Ctx c;
  c.xp = xp;
  c.Wt = Wt;
  const int tid = threadIdx.x;
  c.tid = tid;
  const int lane = tid & 63, wv = tid >> 6;
  const int wr = wv >> 1, wc = wv & 1;
  const int frow = lane & 15, kg = lane >> 4;

#pragma unroll
  for (int k = 0; k < 6; ++k) {
    int gp = k * 256 + tid;
    int g = (gp >= A_GRAN_REAL) ? 0 : swz(gp);  // pad: harmless in-bounds source
    int prow = g / 232;                          // patch row (58 px * 4 granules)
    int rem = g - prow * 232;
    int px = rem >> 2;
    int kg2 = rem & 3;
    c.srcA[k] = ((b * PH + h0 + prow) * PW + px) * CC + kg2 * 8;
  }
#pragma unroll
  for (int i = 0; i < 7; ++i) {
    int t = 16 * i + frow;  // 0..111 within wave's 112-px half
    int rowb = (t >= 56) ? 1 : 0;
    int col = t - 56 * rowb;
    c.gbase[i] = ((2 * wr + rowb + 1) * PW + (col + 1)) * 4 + kg;
  }
#pragma unroll
  for (int j = 0; j < 4; ++j)
    c.gB[j] = ((wc * 64 + 16 * j + frow) * 4 + kg) * 8;

  const f32x4 zero = {0.0f, 0.0f, 0.0f, 0.0f};
#pragma unroll
  for (int i = 0; i < 7; ++i)
#pragma unroll
    for (int j = 0; j < 4; ++j) c.acc[i][j] = zero;

  // prologue: A quarter 0 -> buf 0 (LDS), B slice 0 -> bb[0].
#pragma unroll
  for (int k = 0; k < 6; ++k)
    GLOAD_LDS16(xp + c.srcA[k], lds + (size_t)(k * 256 + tid) * 16);
#pragma unroll
  for (int j = 0; j < 4; ++j)
    c.bb[0][j] = *reinterpret_cast<const bf16x8*>(Wt + c.gB[j]);
  __syncthreads();  // drains A staging (vmcnt(0)) before any wave reads buf 0

  do_steps<0>(c, lds);

  // epilogue: + (1 - D_i[f]), clamp 1.0, NHWC fp32
#pragma unroll
  for (int j = 0; j < 4; ++j) {
    const int col = wc * 64 + 16 * j + frow;
    const float thr = 1.0f - Di[col];
#pragma unroll
    for (int i = 0; i < 7; ++i) {
      const int bt = 16 * i + kg * 4;  // 4-run never crosses the 56 boundary
      const int rowb = (bt >= 56) ? 1 : 0;
      const int wl0 = bt - 56 * rowb;
      const int orow = h0 + 2 * wr + rowb;
      const size_t obase = ((size_t)b * HWP + (size_t)orow * WWD + wl0) * FF + col;
#pragma unroll
      for (int qq = 0; qq < 4; ++qq) {
        float v = c.acc[i][j][qq] + thr;
        out[obase + (size_t)qq * FF] = fminf(v, 1.0f);
      }
    }
  }
}

// ---- fallback (round-0 style, reads W directly) ----
__global__ __launch_bounds__(256) void spiking_conv_fallback(
    const float* __restrict__ x, const float* __restrict__ Wf,
    const float* __restrict__ Di, float* __restrict__ out) {
  __shared__ unsigned short Asm2[128][32];
  __shared__ unsigned short Bsm2[128][32];
  const int tid = threadIdx.x;
  const int m0 = blockIdx.x * 128;
  const int mi = tid & 127;
  const int half = tid >> 7;
  const int m = m0 + mi;
  const int bimg = m / HWP;
  const int p = m - bimg * HWP;
  const int h = p / WWD;
  const int w = p - h * WWD;
  const int baseA = (bimg * CC) * HWP + h * WWD + w;
  const int lane = tid & 63;
  const int wid = tid >> 6;
  const int wr = wid >> 1;
  const int wc = wid & 1;
  const int frow = lane & 15;
  const int kg = lane >> 4;
  f32x4 acc[4][4];
  const f32x4 zero = {0.0f, 0.0f, 0.0f, 0.0f};
#pragma unroll
  for (int i = 0; i < 4; ++i)
#pragma unroll
    for (int j = 0; j < 4; ++j) acc[i][j] = zero;
  for (int r = 0; r < 9; ++r) {
    const int dh = r / 3 - 1;
    const int dw = r - (r / 3) * 3 - 1;
    const int hh = h + dh;
    const int ww2 = w + dw;
    const bool valid = ((unsigned)hh < (unsigned)HH) && ((unsigned)ww2 < (unsigned)WWD);
    const int aoff2 = baseA + dh * WWD + dw + half * 16 * HWP;
    for (int c0 = 0; c0 < CC; c0 += 32) {
      __syncthreads();
      {
        const float* src = x + aoff2 + c0 * HWP;
        us8 v0, v1;
#pragma unroll
        for (int i = 0; i < 8; ++i) {
          float f0 = valid ? src[i * HWP] : 0.0f;
          float f1 = valid ? src[(i + 8) * HWP] : 0.0f;
          v0[i] = f2bf(f0);
          v1[i] = f2bf(f1);
        }
        *reinterpret_cast<us8*>(&Asm2[mi][half * 16]) = v0;
        *reinterpret_cast<us8*>(&Asm2[mi][half * 16 + 8]) = v1;
      }
      {
        us8 v0, v1;
#pragma unroll
        for (int i = 0; i < 8; ++i) {
          int cc2 = c0 + half * 16 + i;
          v0[i] = f2bf(Wf[(cc2 * 9 + r) * FF + mi]);
          v1[i] = f2bf(Wf[((cc2 + 8) * 9 + r) * FF + mi]);
        }
        *reinterpret_cast<us8*>(&Bsm2[mi][half * 16]) = v0;
        *reinterpret_cast<us8*>(&Bsm2[mi][half * 16 + 8]) = v1;
      }
      __syncthreads();
      bf16x8 af[4], bfr[4];
#pragma unroll
      for (int i = 0; i < 4; ++i)
        af[i] = *reinterpret_cast<const bf16x8*>(&Asm2[wr * 64 + i * 16 + frow][kg * 8]);
#pragma unroll
      for (int j = 0; j < 4; ++j)
        bfr[j] = *reinterpret_cast<const bf16x8*>(&Bsm2[wc * 64 + j * 16 + frow][kg * 8]);
#pragma unroll
      for (int i = 0; i < 4; ++i)
#pragma unroll
        for (int j = 0; j < 4; ++j)
          acc[i][j] = __builtin_amdgcn_mfma_f32_16x16x32_bf16(af[i], bfr[j], acc[i][j], 0, 0, 0);
    }
  }
#pragma unroll
  for (int j = 0; j < 4; ++j) {
    const int col = wc * 64 + j * 16 + frow;
    const float thr = 1.0f - Di[col];
#pragma unroll
    for (int i = 0; i < 4; ++i) {
      const int rbase = m0 + wr * 64 + i * 16 + kg * 4;
#pragma unroll
      for (int qq = 0; qq < 4; ++qq) {
        float v = acc[i][j][qq] + thr;
        out[(size_t)(rbase + qq) * FF + col] = fminf(v, 1.0f);
      }
    }
  }
}

extern "C" void kernel_launch(void* const* d_in, const int* in_sizes, int n_in,
                              void* d_out, int out_size, void* d_ws, size_t ws_size,
                              hipStream_t stream) {
  const float* tj = (const float*)d_in[0];
  const float* W = (const float*)d_in[1];
  const float* Di = (const float*)d_in[2];
  float* out = (float*)d_out;

  const size_t wt_bytes = (size_t)NSTEP * 512 * 16;        // 294912
  const size_t xp_bytes = (size_t)BZ * PH * PW * CC * 2;   // 27557888
  unsigned short* Wt = (unsigned short*)d_ws;
  unsigned short* xp = (unsigned short*)((char*)d_ws + wt_bytes);

  bool fast = (ws_size >= wt_bytes + xp_bytes);
  if (fast) {
    prep_w_kernel<<<72, 256, 0, stream>>>(W, Wt);
    prep_x_kernel<<<BZ * PH, 256, 0, stream>>>(tj, xp);
    spiking_conv_main<<<448, 256, 0, stream>>>(xp, Wt, Di, out);
    if (hipGetLastError() != hipSuccess) fast = false;
  }
  if (!fast) {
    spiking_conv_fallback<<<100352 / 128, 256, 0, stream>>>(tj, W, Di, out);
  }
}